// Round 4
// baseline (106.072 us; speedup 1.0000x reference)
//
#include <hip/hip_runtime.h>

// Problem constants
#define Bz 16      // batch
#define Tin 12     // T_IN
#define Ttot 24    // T_TOTAL
#define NN 5000    // nodes
#define Cc 4       // channels
#define KK 16      // neighbors
#define HH 4       // heads
#define OO 12      // T_TOTAL - T_IN
#define TH 48      // Tin * HH
#define G  8       // bt-groups (2 batches each) == number of XCDs
#define JJ 24      // (b,t) pairs per group

typedef float f32x4 __attribute__((ext_vector_type(4)));
__device__ __forceinline__ void nt_store4(float4* p, float4 v) {
    f32x4 t; t.x = v.x; t.y = v.y; t.z = v.z; t.w = v.w;
    __builtin_nontemporal_store(t, (f32x4*)p);
}

// ============ kernel 1: transpose x -> xT2(g, N, 24), XCD-pinned ============
// Flat grid, g = bid & 7 -> same XCD round-robin slot as the main kernel, so
// group g's x-slab (read) and xT2-slab (write) stay in XCD g's L2 for kernel 2.
#define K1_NB 64   // nodes per tile
#define K1_BT 24   // == JJ

__global__ __launch_bounds__(256) void transpose_kernel(
    const float4* __restrict__ x4,   // (BT, N)
    float4* __restrict__ xT2)        // (G, N, JJ)
{
    __shared__ float4 tile[K1_BT][K1_NB + 1];
    const int bid = blockIdx.x;
    const int g   = bid & 7;
    const int n0  = (bid >> 3) * K1_NB;
    const int bt0 = g * K1_BT;
    const int rem = min(K1_NB, NN - n0);
    const int tid = threadIdx.x;

    #pragma unroll
    for (int r = 0; r < (K1_NB * K1_BT) / 256; r++) {
        int tau = r * 256 + tid;
        int j = tau / K1_NB;              // bt within group
        int i = tau % K1_NB;              // node (lane-consecutive)
        if (i < rem)
            tile[j][i] = x4[(size_t)(bt0 + j) * NN + n0 + i];
    }
    __syncthreads();

    #pragma unroll
    for (int r = 0; r < (K1_NB * K1_BT) / 256; r++) {
        int tau = r * 256 + tid;
        int i = tau / K1_BT;              // node
        int j = tau - i * K1_BT;          // j (lane-consecutive, 384 B/node)
        if (i < rem)
            xT2[((size_t)g * NN + n0 + i) * JJ + j] = tile[j][i];
    }
}

// ====== kernel 2: concat copy + gather + aggregate + GEMM + ReLU ============
#define NPB 8                  // nodes per block (5000 = 625 * 8)
#define FST 5                  // feat stride per t   (4 heads + 1 pad)
#define FSB 61                 // feat stride per b_l (12*5 + 1)
#define FSN 123                // feat stride per nl  (2*61 + 1)

__global__ __launch_bounds__(192) void gnn_main_kernel(
    const float4* __restrict__ x4,    // (BT, N)   -- for the concat copy
    const float4* __restrict__ xT2,   // (G, N, JJ)
    const float* __restrict__ dists,  // (N, K)
    const float* __restrict__ W,      // (48, 12)
    const float* __restrict__ bias,   // (12,)
    const int*   __restrict__ nbrs,   // (N, K)
    float4* __restrict__ out4)        // (B*Ttot, N)
{
    __shared__ float4 feat[NPB * FSN];      // 15.7 KB
    __shared__ float4 w4_s[NPB][KK];
    __shared__ float  W_s[TH * OO];
    __shared__ float  bias_s[OO];
    __shared__ int    nbr_s[NPB][KK];

    const int bid = blockIdx.x;
    const int g   = bid & 7;                // XCD-pin (locality only)
    const int n0  = (bid >> 3) * NPB;
    const int tid = threadIdx.x;

    // ---- stage small tensors ----
    for (int i = tid; i < TH * OO; i += 192) W_s[i] = W[i];
    if (tid < OO) bias_s[tid] = bias[tid];
    if (tid < NPB * KK) {
        int nl = tid >> 4, k = tid & 15;
        nbr_s[nl][k] = nbrs[(n0 + nl) * KK + k];
        float d = dists[(n0 + nl) * KK + k];
        float e = -(d * d) * (1.0f / 144.0f);   // h=0 exponent (lam=1/4)
        float4 wv;
        wv.x = expf(e);
        wv.y = expf(2.0f * e);
        wv.z = expf(3.0f * e);
        wv.w = expf(4.0f * e);
        w4_s[nl][k] = wv;
    }

    // ---- concat copy: out[b,t,n0+nl] = x[bt,n0+nl] (L2-hot slab, nt out) ----
    {
        const int j  = tid >> 3;            // 0..23
        const int nl = tid & 7;             // lane-consecutive -> 128 B chunks
        const int bt = g * JJ + j;
        const int b  = bt / Tin, t = bt - b * Tin;
        float4 v = x4[(size_t)bt * NN + n0 + nl];
        nt_store4(&out4[(size_t)(b * Ttot + t) * NN + n0 + nl], v);
    }
    __syncthreads();

    // ---- phase A: gather (384 B rows, L2-resident slab) + aggregate ----
    {
        const int nl  = tid / JJ;            // 0..7
        const int j   = tid - nl * JJ;       // 0..23 (lane-consecutive)
        const int b_l = j / Tin;
        const int t   = j - b_l * Tin;
        const float4* xg = xT2 + (size_t)g * NN * JJ;

        float4 a0 = {0,0,0,0}, a1 = {0,0,0,0}, a2 = {0,0,0,0}, a3 = {0,0,0,0};
        #pragma unroll
        for (int k = 0; k < KK; k++) {
            float4 xv = xg[(size_t)nbr_s[nl][k] * JJ + j];
            float4 wv = w4_s[nl][k];
            a0.x += wv.x * xv.x; a0.y += wv.x * xv.y; a0.z += wv.x * xv.z; a0.w += wv.x * xv.w;
            a1.x += wv.y * xv.x; a1.y += wv.y * xv.y; a1.z += wv.y * xv.z; a1.w += wv.y * xv.w;
            a2.x += wv.z * xv.x; a2.y += wv.z * xv.y; a2.z += wv.z * xv.z; a2.w += wv.z * xv.w;
            a3.x += wv.w * xv.x; a3.y += wv.w * xv.y; a3.z += wv.w * xv.z; a3.w += wv.w * xv.w;
        }
        const int base = nl * FSN + b_l * FSB + t * FST;
        feat[base + 0] = a0;
        feat[base + 1] = a1;
        feat[base + 2] = a2;
        feat[base + 3] = a3;
    }
    __syncthreads();

    // ---- phase B: (48 -> 12) GEMM + bias + ReLU; full-line nt stores ----
    {
        const int nl  = tid & 7;             // lane-consecutive -> 128 B line
        const int bo  = tid >> 3;            // 0..23
        const int b_l = bo / OO;
        const int o   = bo - b_l * OO;
        const float bz = bias_s[o];
        float4 acc = {bz, bz, bz, bz};
        const int fbase = nl * FSN + b_l * FSB;
        #pragma unroll
        for (int t = 0; t < Tin; t++) {
            #pragma unroll
            for (int h = 0; h < HH; h++) {
                float  wv = W_s[(t * HH + h) * OO + o];
                float4 f  = feat[fbase + t * FST + h];
                acc.x += wv * f.x; acc.y += wv * f.y;
                acc.z += wv * f.z; acc.w += wv * f.w;
            }
        }
        acc.x = fmaxf(acc.x, 0.0f); acc.y = fmaxf(acc.y, 0.0f);
        acc.z = fmaxf(acc.z, 0.0f); acc.w = fmaxf(acc.w, 0.0f);
        const int b = g * 2 + b_l;
        nt_store4(&out4[(size_t)(b * Ttot + Tin + o) * NN + n0 + nl], acc);
    }
}

extern "C" void kernel_launch(void* const* d_in, const int* in_sizes, int n_in,
                              void* d_out, int out_size, void* d_ws, size_t ws_size,
                              hipStream_t stream) {
    const float* x     = (const float*)d_in[0];
    const float* dists = (const float*)d_in[1];
    const float* W     = (const float*)d_in[2];
    const float* bias  = (const float*)d_in[3];
    const int*   nbrs  = (const int*)d_in[4];
    float4* out4 = (float4*)d_out;
    float4* xT2  = (float4*)d_ws;     // G*NN*JJ*16 B = 15.36 MB of ws

    const int ntiles = (NN + K1_NB - 1) / K1_NB;   // 79
    hipLaunchKernelGGL(transpose_kernel, dim3(ntiles * G), dim3(256), 0, stream,
                       (const float4*)x, xT2);

    hipLaunchKernelGGL(gnn_main_kernel, dim3((NN / NPB) * G), dim3(192), 0, stream,
                       (const float4*)x, (const float4*)xT2,
                       dists, W, bias, nbrs, out4);
}